// Round 14
// baseline (204.085 us; speedup 1.0000x reference)
//
#include <hip/hip_runtime.h>
#include <hip/hip_bf16.h>

// InputProjection: shared LayerNorm + Q/K/V projections (fp32 in, fp32 out).
// R14: DS-traffic re-shape. Fitted HW model from R12/R13: ds_read_b128 eff.
// ~24 cyc/CU on the SHARED per-CU DS pipe -> kernel is DS-pipe-bound at
// wave-tile 128x64 (48 reads / 128 MFMA). New: 256^2 tile, 4 waves, wave
// tile 128x128 (16 reads / 64 MFMA, 1.5x better ratio, only 4 waves on the
// pipe). acc[8][8] (AGPR), launch_bounds(256,1). 3 LDS buffers (96 KiB),
// stage distance 3, uniform vmcnt(8), phase = {stage t+3; RD t+1; PIN;
// 64 MFMA on t; lgkm0; vmcnt(8); barrier}.

#define HIDDEN 1024
#define NTOK   32768

typedef __bf16 bf16x8 __attribute__((ext_vector_type(8)));
typedef float  f32x4  __attribute__((ext_vector_type(4)));

#define GLOBAL_AS(p) ((const __attribute__((address_space(1))) void*)(p))
#define LDS_AS(p)    ((__attribute__((address_space(3))) void*)(p))

__device__ __forceinline__ unsigned short f2bf(float f) {
  union { float f; unsigned int i; } x; x.f = f;
  unsigned int r = x.i + 0x7FFFu + ((x.i >> 16) & 1u);   // RNE
  return (unsigned short)(r >> 16);
}

// ---------------- K1: LayerNorm (fp32 in, bf16 out) + weight cvt ----------------
__global__ __launch_bounds__(256) void ln_cvt_kernel(
    const float* __restrict__ x,
    const float* __restrict__ gamma,
    const float* __restrict__ beta,
    const float* __restrict__ wq,
    const float* __restrict__ wk,
    const float* __restrict__ wv,
    unsigned short* __restrict__ xn,
    unsigned short* __restrict__ wb) {
  const int bid = blockIdx.x;
  const int t   = threadIdx.x;
  if (bid < NTOK) {
    const size_t base = (size_t)bid * HIDDEN;
    const float4 v = ((const float4*)(x + base))[t];
    float s  = v.x + v.y + v.z + v.w;
    float s2 = v.x*v.x + v.y*v.y + v.z*v.z + v.w*v.w;
#pragma unroll
    for (int off = 32; off >= 1; off >>= 1) {
      s  += __shfl_xor(s,  off);
      s2 += __shfl_xor(s2, off);
    }
    __shared__ float red[8];
    const int w = t >> 6;
    if ((t & 63) == 0) { red[w] = s; red[4 + w] = s2; }
    __syncthreads();
    s  = red[0] + red[1] + red[2] + red[3];
    s2 = red[4] + red[5] + red[6] + red[7];
    const float mu   = s * (1.0f / HIDDEN);
    const float rstd = rsqrtf(s2 * (1.0f / HIDDEN) - mu * mu + 1e-5f);
    const float4 g  = ((const float4*)gamma)[t];
    const float4 bb = ((const float4*)beta)[t];
    ushort4 o;
    o.x = f2bf((v.x - mu) * rstd * g.x + bb.x);
    o.y = f2bf((v.y - mu) * rstd * g.y + bb.y);
    o.z = f2bf((v.z - mu) * rstd * g.z + bb.z);
    o.w = f2bf((v.w - mu) * rstd * g.w + bb.w);
    ((ushort4*)(xn + base))[t] = o;
  } else {
    const int b2 = bid - NTOK;           // 0..1535; 1024 wq, 256 wk, 256 wv
    const float* src;
    int off;
    if (b2 < 1024)      { src = wq; off = b2; }
    else if (b2 < 1280) { src = wk; off = b2 - 1024; }
    else                { src = wv; off = b2 - 1280; }
    const float4 v = ((const float4*)src)[off * 256 + t];
    ushort4 o;
    o.x = f2bf(v.x); o.y = f2bf(v.y); o.z = f2bf(v.z); o.w = f2bf(v.w);
    ((ushort4*)wb)[b2 * 256 + t] = o;
  }
}

// ---------------- K2: 4-wave big-wave-tile QKV GEMM ----------------
// 768 blocks (128 M x 6 N), 256 threads (4 waves, 2M x 2N), wave tile 128x128.
__global__ __launch_bounds__(256, 1) void qkv_gemm(
    const unsigned short* __restrict__ xn,
    const unsigned short* __restrict__ wqb,
    const float* __restrict__ bq,
    const float* __restrict__ bk,
    const float* __restrict__ bv,
    float* __restrict__ out) {
  // [3 buf][256 rows][32 k] bf16 per operand = 48 KiB each, 96 KiB total
  __shared__ unsigned short Alds[24576];
  __shared__ unsigned short Blds[24576];

  const int bid = blockIdx.x;
  const int swz = (bid & 7) * 96 + (bid >> 3);   // bijective: 768 % 8 == 0
  const int mt  = swz / 6;
  const int nt  = swz % 6;
  const int brow = mt * 256;

  const unsigned short* wbase; const float* biasptr;
  int segcol; size_t obase; int hg;
  if (nt < 4)       { wbase = wqb + (size_t)nt * 256 * HIDDEN;  biasptr = bq; segcol = nt * 256; obase = 0u;        hg = 16; }
  else if (nt == 4) { wbase = wqb + (size_t)1024 * HIDDEN;      biasptr = bk; segcol = 0;        obase = 33554432u; hg = 4;  }
  else              { wbase = wqb + (size_t)1280 * HIDDEN;      biasptr = bv; segcol = 0;        obase = 41943040u; hg = 4;  }

  const int t = threadIdx.x;
  const int w = t >> 6, lane = t & 63;
  const int wm = w >> 1, wn = w & 1;               // wave tile: rows wm*128, cols wn*128
  const int l15 = lane & 15, hi = lane >> 4;

  // staging: wave w covers rows w*64..w*64+63 (4 instr x 16 rows each).
  // lane: row = w*64 + i*16 + (lane>>2), granule = (lane&3) ^ ((row>>1)&3)
  const int sr  = w * 64 + (lane >> 2);
  const int scg = ((lane & 3) ^ ((lane >> 3) & 3)) * 8;
  const unsigned short* aST = xn    + (size_t)(brow + sr) * HIDDEN + scg;
  const unsigned short* bST = wbase + (size_t)sr * HIDDEN + scg;
  const int ldsq = w * 2048;   // wave-uniform elems within buffer; HW adds lane*16B

  // ds_read: addr = bufOff + row*32 + (hi ^ ((row>>1)&3))*8   [HW-proven R13]
  const int rdx  = (hi ^ ((l15 >> 1) & 3)) * 8;
  const int rowA = wm * 128 + l15;
  const int rowB = wn * 128 + l15;

  f32x4 acc[8][8];
#pragma unroll
  for (int m = 0; m < 8; ++m)
#pragma unroll
    for (int n = 0; n < 8; ++n) acc[m][n] = (f32x4){0.f, 0.f, 0.f, 0.f};
  bf16x8 a0[8], b0[8], a1[8], b1[8];

#define ST(BUFO, KT) do { _Pragma("unroll")                                     \
    for (int i = 0; i < 4; ++i) {                                               \
      __builtin_amdgcn_global_load_lds(                                         \
          GLOBAL_AS(aST + (size_t)(KT) * 32 + (size_t)i * 16 * HIDDEN),         \
          LDS_AS(Alds + (BUFO) + ldsq + i * 512), 16, 0, 0);                    \
      __builtin_amdgcn_global_load_lds(                                         \
          GLOBAL_AS(bST + (size_t)(KT) * 32 + (size_t)i * 16 * HIDDEN),         \
          LDS_AS(Blds + (BUFO) + ldsq + i * 512), 16, 0, 0);                    \
    }                                                                           \
  } while (0)
#define RD(SA, SB, BUFO) do { _Pragma("unroll")                                 \
    for (int m = 0; m < 8; ++m)                                                 \
      SA[m] = *(const bf16x8*)(Alds + (BUFO) + (rowA + m * 16) * 32 + rdx);     \
    _Pragma("unroll")                                                           \
    for (int n = 0; n < 8; ++n)                                                 \
      SB[n] = *(const bf16x8*)(Blds + (BUFO) + (rowB + n * 16) * 32 + rdx);     \
  } while (0)
#define MMX(SA, SB) do { _Pragma("unroll")                                      \
    for (int m = 0; m < 8; ++m)                                                 \
      _Pragma("unroll") for (int n = 0; n < 8; ++n)                             \
        acc[m][n] = __builtin_amdgcn_mfma_f32_16x16x32_bf16(SA[m], SB[n], acc[m][n], 0, 0, 0); \
  } while (0)
#define PIN __builtin_amdgcn_sched_barrier(0)
#define ENDPH(VMN) do {                                                         \
    asm volatile("s_waitcnt lgkmcnt(0)" ::: "memory");                          \
    asm volatile("s_waitcnt vmcnt(" #VMN ")" ::: "memory");                     \
    PIN; __builtin_amdgcn_s_barrier(); PIN;                                     \
  } while (0)

  // prologue: stage tiles 0,1,2 into bufs 0,1,2 (24 loads); drain tile 0;
  // read tile-0 frags; barrier (R11 lesson: stage at T=0 overwrites buf0).
  ST(0, 0); ST(8192, 1); ST(16384, 2);
  asm volatile("s_waitcnt vmcnt(16)" ::: "memory");
  PIN; __builtin_amdgcn_s_barrier(); PIN;
  RD(a0, b0, 0);
  asm volatile("s_waitcnt lgkmcnt(0)" ::: "memory");
  PIN; __builtin_amdgcn_s_barrier(); PIN;

  // phases T: stage tile T+3 -> buf (T%3); RD tile T+1 from buf ((T+1)%3);
  // MMX tile T. Uniform vmcnt(8): end of T drains all but newest stage.
  for (int T = 0; T < 28; T += 2) {
    const int bS0 = (T % 3) * 8192, bR0 = ((T + 1) % 3) * 8192;
    ST(bS0, T + 3); RD(a1, b1, bR0); PIN; MMX(a0, b0); ENDPH(8);
    const int bS1 = ((T + 1) % 3) * 8192, bR1 = ((T + 2) % 3) * 8192;
    ST(bS1, T + 4); RD(a0, b0, bR1); PIN; MMX(a1, b1); ENDPH(8);
  }
  // T=28 (stage t31), 29, 30, 31
  ST(8192, 31); RD(a1, b1, 16384); PIN; MMX(a0, b0); ENDPH(8);   // t28; RD t29
  RD(a0, b0, 0);                   PIN; MMX(a1, b1); ENDPH(0);   // t29; RD t30
  RD(a1, b1, 8192);                PIN; MMX(a0, b0);             // t30; RD t31
  asm volatile("s_waitcnt lgkmcnt(0)" ::: "memory");
  PIN; __builtin_amdgcn_s_barrier(); PIN;
  MMX(a1, b1);                                                   // t31

#undef ST
#undef RD
#undef MMX
#undef ENDPH

  // ---- epilogue: coalesced. Wave output = contiguous-per-head [128 tok][128 col]
  // (2 heads/groups of 64). Per 16-token chunk: acc+bias -> LDS rows of 132 f32
  // (2-way max writes, conflict-free float4 reads) -> stores (2 rows/pass,
  // each 16-lane group writes a 256B segment). Per-wave-disjoint LDS.
  float* ep = (float*)Alds;               // 4 waves x 16 x 132 f32 = 33792 B
  const int epb = w * 2112;
  const int tok0 = brow + wm * 128;
  float biasv[8];
#pragma unroll
  for (int n = 0; n < 8; ++n) biasv[n] = biasptr[segcol + wn * 128 + n * 16 + l15];

#pragma unroll
  for (int m = 0; m < 8; ++m) {
#pragma unroll
    for (int n = 0; n < 8; ++n)
#pragma unroll
      for (int j = 0; j < 4; ++j)
        ep[epb + (hi * 4 + j) * 132 + n * 16 + l15] = acc[m][n][j] + biasv[n];
    asm volatile("s_waitcnt lgkmcnt(0)" ::: "memory");
    PIN;
#pragma unroll
    for (int pass = 0; pass < 8; ++pass) {
      const int r = pass * 2 + (lane >> 5);
      const int c = (lane & 31) * 4;
      const float4 v = *(const float4*)(ep + epb + r * 132 + c);
      const int ncol = segcol + wn * 128 + c;
      const int g = ncol >> 6, d = ncol & 63;
      const int token = tok0 + m * 16 + r;
      const int b_ = token >> 12, s = token & 4095;
      *(float4*)(out + obase + (size_t)(b_ * hg + g) * 262144u
                     + (size_t)s * 64u + d) = v;
    }
  }
#undef PIN
}

extern "C" void kernel_launch(void* const* d_in, const int* in_sizes, int n_in,
                              void* d_out, int out_size, void* d_ws, size_t ws_size,
                              hipStream_t stream) {
  const float* x  = (const float*)d_in[0];
  const float* wq = (const float*)d_in[1];
  const float* wk = (const float*)d_in[2];
  const float* wv = (const float*)d_in[3];
  const float* bq = (const float*)d_in[4];
  const float* bk = (const float*)d_in[5];
  const float* bv = (const float*)d_in[6];
  const float* g  = (const float*)d_in[7];
  const float* be = (const float*)d_in[8];
  float* out = (float*)d_out;

  unsigned short* xn = (unsigned short*)d_ws;                          // 64 MiB
  unsigned short* wb = (unsigned short*)((char*)d_ws + (64u << 20));   // 3 MiB (wq|wk|wv bf16)

  ln_cvt_kernel<<<NTOK + 1536, 256, 0, stream>>>(x, g, be, wq, wk, wv, xn, wb);
  qkv_gemm<<<768, 256, 0, stream>>>(xn, wb, bq, bk, bv, out);
}